// Round 4
// baseline (510.237 us; speedup 1.0000x reference)
//
#include <hip/hip_runtime.h>
#include <cstdint>

// y[16384,2048] = x(f32) @ W(int8-valued int32, [in,out]) * scale[1,2048]
// R4: revert to R2 geometry (16x16x32, linear LDS). Structural change:
// B fragments loaded global->VGPR with 1-iter prefetch (W^T is 8MB, L2/L3
// resident) -> LDS traffic/block-iter 48KB -> 24KB (LDS was the binding pipe
// at ~93us aggregate vs 66us MFMA floor). A stays on the global_load_lds DMA
// path. Converts merged into one launch.

#define M_TOK 16384
#define K_DIM 2048
#define N_DIM 2048
#define BK 32

typedef _Float16 f16;
typedef f16 f16x4 __attribute__((ext_vector_type(4)));
typedef f16 f16x8 __attribute__((ext_vector_type(8)));
typedef float f32x4 __attribute__((ext_vector_type(4)));

// ---------------------------------------------------------------------------
// Merged pre-pass: blocks [0,1024) transpose W int32[K][N] -> W^T f16[N][K];
// blocks [1024, 5120) convert x f32 -> f16 (RNE).
// ---------------------------------------------------------------------------
__global__ void convert_kernel(const float* __restrict__ x, const int* __restrict__ w,
                               f16* __restrict__ xh, f16* __restrict__ wt) {
  const int tid = threadIdx.x;
  if (blockIdx.x < 1024) {
    __shared__ f16 tile[64][68];           // [n_local][k_local], padded
    const int nb = (blockIdx.x & 31) * 64;
    const int kb = (blockIdx.x >> 5) * 64;
    const int cq = tid & 15;
    const int rr = tid >> 4;
#pragma unroll
    for (int g = 0; g < 4; ++g) {
      int krow = g * 16 + rr;
      const int* p = w + (size_t)(kb + krow) * N_DIM + nb + cq * 4;
      int4 v = *(const int4*)p;            // coalesced along n
      tile[cq * 4 + 0][krow] = (f16)(float)v.x;
      tile[cq * 4 + 1][krow] = (f16)(float)v.y;
      tile[cq * 4 + 2][krow] = (f16)(float)v.z;
      tile[cq * 4 + 3][krow] = (f16)(float)v.w;
    }
    __syncthreads();
#pragma unroll
    for (int g = 0; g < 4; ++g) {
      int nrow = g * 16 + rr;
      f16x4 o;
#pragma unroll
      for (int j = 0; j < 4; ++j) o[j] = tile[nrow][cq * 4 + j];
      *(f16x4*)(wt + (size_t)(nb + nrow) * K_DIM + kb + cq * 4) = o;
    }
  } else {
    const int n8 = (M_TOK * K_DIM) / 8;
    const int nthreads = 4096 * 256;
    for (int i = (blockIdx.x - 1024) * 256 + tid; i < n8; i += nthreads) {
      float4 v0 = ((const float4*)x)[i * 2];
      float4 v1 = ((const float4*)x)[i * 2 + 1];
      f16x8 h;
      h[0] = (f16)v0.x; h[1] = (f16)v0.y; h[2] = (f16)v0.z; h[3] = (f16)v0.w;
      h[4] = (f16)v1.x; h[5] = (f16)v1.y; h[6] = (f16)v1.z; h[7] = (f16)v1.w;
      ((f16x8*)xh)[i] = h;
    }
  }
}

// ---------------------------------------------------------------------------
// Main GEMM: A via global_load_lds DMA (8KB tile), B direct global->VGPR
// with one-iteration prefetch. 128x128 block, 4 waves, 4x4 16x16x32 MFMA.
// ---------------------------------------------------------------------------
__device__ __forceinline__ void async_load16(const void* g, void* l) {
  __builtin_amdgcn_global_load_lds((__attribute__((address_space(1))) void*)g,
                                   (__attribute__((address_space(3))) void*)l,
                                   16, 0, 0);
}

__global__ __launch_bounds__(256, 4) void gemm_f16(
    const f16* __restrict__ xh, const f16* __restrict__ wt,
    const float* __restrict__ scale, float* __restrict__ out) {
  __shared__ __align__(16) f16 sA[128 * BK];    // A tile [m][k] 8KB, row=64B

  const int tid = threadIdx.x;
  const int wave = tid >> 6;
  const int lane = tid & 63;
  const int m0 = blockIdx.y * 128;
  const int n0 = blockIdx.x * 128;
  const int wm = (wave & 1) * 64;
  const int wn = (wave >> 1) * 64;

  // A DMA staging: 8 chunks of 1KB (16 rows each); wave fills {2w, 2w+1}.
  // chunk c, lane i -> LDS row c*16 + i/4, k-offset (i%4)*8 (lane*16B rule)
  const int c0 = wave * 2;
  const int rowA = c0 * 16 + (lane >> 2);
  const int kq8 = (lane & 3) * 8;
  const f16* gA0 = xh + (size_t)(m0 + rowA) * K_DIM + kq8;
  const f16* gA1 = gA0 + (size_t)16 * K_DIM;
  f16* lA0 = sA + c0 * 512;
  f16* lA1 = lA0 + 512;

  // MFMA fragment geometry (16x16x32): [row=lane&15][k=(lane>>4)*8 + j]
  const int fr = lane & 15;
  const int fq = (lane >> 4) * 8;

  // B fragment global base: row n0+wn+t*16+fr, k-offset fq. 4 lanes/row read
  // 64B contiguous -> L2-friendly. Re-reads served by L2/L3 (wt = 8MB).
  const f16* gBf = wt + (size_t)(n0 + wn + fr) * K_DIM + fq;

  f32x4 acc[4][4] = {};
  f16x8 bCur[4], bNext[4];
#pragma unroll
  for (int t = 0; t < 4; ++t)
    bNext[t] = *(const f16x8*)(gBf + (size_t)t * 16 * K_DIM);   // k0 = 0

  for (int k0 = 0; k0 < K_DIM; k0 += BK) {
    async_load16(gA0 + k0, lA0);
    async_load16(gA1 + k0, lA1);
    __syncthreads();   // drains DMA -> A tile visible

    f16x8 a[4];
#pragma unroll
    for (int t = 0; t < 4; ++t)
      a[t] = *(const f16x8*)&sA[(wm + t * 16 + fr) * BK + fq];

#pragma unroll
    for (int t = 0; t < 4; ++t) bCur[t] = bNext[t];

    // prefetch next iteration's B (wraps harmlessly to k=0 on last iter);
    // loads stay in flight through the MFMA phase below.
    const int kpf = (k0 + BK) & (K_DIM - 1);
#pragma unroll
    for (int t = 0; t < 4; ++t)
      bNext[t] = *(const f16x8*)(gBf + (size_t)t * 16 * K_DIM + kpf);

#pragma unroll
    for (int mm = 0; mm < 4; ++mm)
#pragma unroll
      for (int nn = 0; nn < 4; ++nn)
        acc[mm][nn] = __builtin_amdgcn_mfma_f32_16x16x32_f16(a[mm], bCur[nn], acc[mm][nn], 0, 0, 0);

    __syncthreads();   // protect A LDS from next iteration's DMA
  }

  // Epilogue: C/D layout col(n)=lane&15, row(m)=(lane>>4)*4+reg; scale[n]
#pragma unroll
  for (int nn = 0; nn < 4; ++nn) {
    int col = n0 + wn + nn * 16 + fr;
    float s = scale[col];
#pragma unroll
    for (int mm = 0; mm < 4; ++mm) {
      int rbase = m0 + wm + mm * 16 + (lane >> 4) * 4;
      f32x4 v = acc[mm][nn];
#pragma unroll
      for (int r = 0; r < 4; ++r)
        out[(size_t)(rbase + r) * N_DIM + col] = v[r] * s;
    }
  }
}

// ---------------------------------------------------------------------------
extern "C" void kernel_launch(void* const* d_in, const int* in_sizes, int n_in,
                              void* d_out, int out_size, void* d_ws, size_t ws_size,
                              hipStream_t stream) {
  const float* x     = (const float*)d_in[0];
  const float* scale = (const float*)d_in[1];
  const int* w       = (const int*)d_in[2];   // integer inputs arrive as int32
  float* out         = (float*)d_out;

  // workspace: x_h f16 (64MB) | W^T f16 (8MB)
  char* ws = (char*)d_ws;
  f16* xh = (f16*)ws;
  f16* wt = (f16*)(ws + (size_t)M_TOK * K_DIM * 2);

  convert_kernel<<<5120, 256, 0, stream>>>(x, w, xh, wt);
  gemm_f16<<<dim3(N_DIM / 128, M_TOK / 128), 256, 0, stream>>>(xh, wt, scale, out);
}

// Round 5
// 407.053 us; speedup vs baseline: 1.2535x; 1.2535x over previous
//
#include <hip/hip_runtime.h>
#include <cstdint>

// y[16384,2048] = x(f32) @ W(int8-valued int32, [in,out]) * scale[1,2048]
// R5: R2 geometry (16x16x32 MFMA, A+B via global_load_lds DMA, linear LDS)
// + double-buffered LDS with ONE barrier per K-iter. The barrier's vmcnt(0)
// drain now lands ~180cy after DMA issue (covered by ds_read+MFMA) instead of
// immediately after, and barrier count halves. R4 lesson: global->VGPR
// prefetch is useless (compiler drains vmcnt(0) at every barrier).

#define M_TOK 16384
#define K_DIM 2048
#define N_DIM 2048
#define BK 32
#define TILE (128 * BK)   // f16 elements per buffer

typedef _Float16 f16;
typedef f16 f16x4 __attribute__((ext_vector_type(4)));
typedef f16 f16x8 __attribute__((ext_vector_type(8)));
typedef float f32x4 __attribute__((ext_vector_type(4)));

// ---------------------------------------------------------------------------
// Merged pre-pass: blocks [0,1024) transpose W int32[K][N] -> W^T f16[N][K];
// blocks [1024, 5120) convert x f32 -> f16 (RNE).
// ---------------------------------------------------------------------------
__global__ void convert_kernel(const float* __restrict__ x, const int* __restrict__ w,
                               f16* __restrict__ xh, f16* __restrict__ wt) {
  const int tid = threadIdx.x;
  if (blockIdx.x < 1024) {
    __shared__ f16 tile[64][68];           // [n_local][k_local], padded
    const int nb = (blockIdx.x & 31) * 64;
    const int kb = (blockIdx.x >> 5) * 64;
    const int cq = tid & 15;
    const int rr = tid >> 4;
#pragma unroll
    for (int g = 0; g < 4; ++g) {
      int krow = g * 16 + rr;
      const int* p = w + (size_t)(kb + krow) * N_DIM + nb + cq * 4;
      int4 v = *(const int4*)p;            // coalesced along n
      tile[cq * 4 + 0][krow] = (f16)(float)v.x;
      tile[cq * 4 + 1][krow] = (f16)(float)v.y;
      tile[cq * 4 + 2][krow] = (f16)(float)v.z;
      tile[cq * 4 + 3][krow] = (f16)(float)v.w;
    }
    __syncthreads();
#pragma unroll
    for (int g = 0; g < 4; ++g) {
      int nrow = g * 16 + rr;
      f16x4 o;
#pragma unroll
      for (int j = 0; j < 4; ++j) o[j] = tile[nrow][cq * 4 + j];
      *(f16x4*)(wt + (size_t)(nb + nrow) * K_DIM + kb + cq * 4) = o;
    }
  } else {
    const int n8 = (M_TOK * K_DIM) / 8;
    const int nthreads = 4096 * 256;
    for (int i = (blockIdx.x - 1024) * 256 + tid; i < n8; i += nthreads) {
      float4 v0 = ((const float4*)x)[i * 2];
      float4 v1 = ((const float4*)x)[i * 2 + 1];
      f16x8 h;
      h[0] = (f16)v0.x; h[1] = (f16)v0.y; h[2] = (f16)v0.z; h[3] = (f16)v0.w;
      h[4] = (f16)v1.x; h[5] = (f16)v1.y; h[6] = (f16)v1.z; h[7] = (f16)v1.w;
      ((f16x8*)xh)[i] = h;
    }
  }
}

// ---------------------------------------------------------------------------
// Main GEMM: 128x128 block, 4 waves, 4x4 16x16x32 MFMA, double-buffered LDS,
// one barrier per K-iteration.
// ---------------------------------------------------------------------------
__device__ __forceinline__ void async_load16(const void* g, void* l) {
  __builtin_amdgcn_global_load_lds((__attribute__((address_space(1))) void*)g,
                                   (__attribute__((address_space(3))) void*)l,
                                   16, 0, 0);
}

__global__ __launch_bounds__(256) void gemm_f16(
    const f16* __restrict__ xh, const f16* __restrict__ wt,
    const float* __restrict__ scale, float* __restrict__ out) {
  __shared__ __align__(16) f16 sA[2 * TILE];    // 2 x 8KB A tiles [m][k]
  __shared__ __align__(16) f16 sB[2 * TILE];    // 2 x 8KB B^T tiles [n][k]

  const int tid = threadIdx.x;
  const int wave = tid >> 6;
  const int lane = tid & 63;
  const int m0 = blockIdx.y * 128;
  const int n0 = blockIdx.x * 128;
  const int wm = (wave & 1) * 64;
  const int wn = (wave >> 1) * 64;

  // DMA staging: each tile = 8 chunks of 1KB (16 rows); wave fills {2w,2w+1}.
  // chunk c, lane i -> LDS row c*16 + i/4, k-offset (i%4)*8 (lane*16B rule)
  const int c0 = wave * 2;
  const int rowA = c0 * 16 + (lane >> 2);
  const int kq8 = (lane & 3) * 8;
  const f16* gA0 = xh + (size_t)(m0 + rowA) * K_DIM + kq8;
  const f16* gA1 = gA0 + (size_t)16 * K_DIM;
  const f16* gB0 = wt + (size_t)(n0 + rowA) * K_DIM + kq8;
  const f16* gB1 = gB0 + (size_t)16 * K_DIM;
  f16* lA0 = sA + c0 * 512;  f16* lA1 = lA0 + 512;
  f16* lB0 = sB + c0 * 512;  f16* lB1 = lB0 + 512;

  // MFMA fragment geometry (16x16x32): [row=lane&15][k=(lane>>4)*8 + j]
  const int fr = lane & 15;
  const int fq = (lane >> 4) * 8;

  f32x4 acc[4][4] = {};

  // Prologue: stage tile 0 into buffer 0
  async_load16(gA0, lA0);
  async_load16(gA1, lA1);
  async_load16(gB0, lB0);
  async_load16(gB1, lB1);
  __syncthreads();

  int buf = 0;
  for (int k0 = 0; k0 < K_DIM; k0 += BK) {
    const int nb = buf ^ 1;
    // Prefetch next tile into the other buffer; loads stay in flight through
    // the ds_read + MFMA phase below and are drained at the barrier.
    if (k0 + BK < K_DIM) {
      const int kp = k0 + BK;
      async_load16(gA0 + kp, lA0 + nb * TILE);
      async_load16(gA1 + kp, lA1 + nb * TILE);
      async_load16(gB0 + kp, lB0 + nb * TILE);
      async_load16(gB1 + kp, lB1 + nb * TILE);
    }

    const f16* bA = sA + buf * TILE;
    const f16* bB = sB + buf * TILE;
    f16x8 a[4], b[4];
#pragma unroll
    for (int t = 0; t < 4; ++t) {
      a[t] = *(const f16x8*)&bA[(wm + t * 16 + fr) * BK + fq];
      b[t] = *(const f16x8*)&bB[(wn + t * 16 + fr) * BK + fq];
    }
#pragma unroll
    for (int mm = 0; mm < 4; ++mm)
#pragma unroll
      for (int nn = 0; nn < 4; ++nn)
        acc[mm][nn] = __builtin_amdgcn_mfma_f32_16x16x32_f16(a[mm], b[nn], acc[mm][nn], 0, 0, 0);

    __syncthreads();   // single barrier: drains next-tile DMA, protects buf reuse
    buf = nb;
  }

  // Epilogue: C/D layout col(n)=lane&15, row(m)=(lane>>4)*4+reg; scale[n]
#pragma unroll
  for (int nn = 0; nn < 4; ++nn) {
    int col = n0 + wn + nn * 16 + fr;
    float s = scale[col];
#pragma unroll
    for (int mm = 0; mm < 4; ++mm) {
      int rbase = m0 + wm + mm * 16 + (lane >> 4) * 4;
      f32x4 v = acc[mm][nn];
#pragma unroll
      for (int r = 0; r < 4; ++r)
        out[(size_t)(rbase + r) * N_DIM + col] = v[r] * s;
    }
  }
}

// ---------------------------------------------------------------------------
extern "C" void kernel_launch(void* const* d_in, const int* in_sizes, int n_in,
                              void* d_out, int out_size, void* d_ws, size_t ws_size,
                              hipStream_t stream) {
  const float* x     = (const float*)d_in[0];
  const float* scale = (const float*)d_in[1];
  const int* w       = (const int*)d_in[2];   // integer inputs arrive as int32
  float* out         = (float*)d_out;

  // workspace: x_h f16 (64MB) | W^T f16 (8MB)
  char* ws = (char*)d_ws;
  f16* xh = (f16*)ws;
  f16* wt = (f16*)(ws + (size_t)M_TOK * K_DIM * 2);

  convert_kernel<<<5120, 256, 0, stream>>>(x, w, xh, wt);
  gemm_f16<<<dim3(N_DIM / 128, M_TOK / 128), 256, 0, stream>>>(xh, wt, scale, out);
}

// Round 6
// 395.412 us; speedup vs baseline: 1.2904x; 1.0294x over previous
//
#include <hip/hip_runtime.h>
#include <cstdint>

// y[16384,2048] = x(f32) @ W(int8-valued int32, [in,out]) * scale[1,2048]
// R6: tile-aspect change. 256x128 block, 4 waves, wave tile 128x64
// (8x4 of 16x16x32 MFMA). LDS read volume per FLOP drops 0.75x vs 128^2,
// making MFMA (66us/CU) the binding pipe instead of LDS (was 80us/CU).
// Keeps R2's proven skeleton: both operands via global_load_lds DMA,
// linear LDS, 2-barrier K-loop, single-buffered (R5 showed dbuf is
// VALU-negative; R4 showed VGPR prefetch dies at barrier vmcnt drains).

#define M_TOK 16384
#define K_DIM 2048
#define N_DIM 2048
#define BM 256
#define BN 128
#define BK 32

typedef _Float16 f16;
typedef f16 f16x4 __attribute__((ext_vector_type(4)));
typedef f16 f16x8 __attribute__((ext_vector_type(8)));
typedef float f32x4 __attribute__((ext_vector_type(4)));

// ---------------------------------------------------------------------------
// Merged pre-pass: blocks [0,1024) transpose W int32[K][N] -> W^T f16[N][K];
// blocks [1024, 5120) convert x f32 -> f16 (RNE).
// ---------------------------------------------------------------------------
__global__ void convert_kernel(const float* __restrict__ x, const int* __restrict__ w,
                               f16* __restrict__ xh, f16* __restrict__ wt) {
  const int tid = threadIdx.x;
  if (blockIdx.x < 1024) {
    __shared__ f16 tile[64][68];           // [n_local][k_local], padded
    const int nb = (blockIdx.x & 31) * 64;
    const int kb = (blockIdx.x >> 5) * 64;
    const int cq = tid & 15;
    const int rr = tid >> 4;
#pragma unroll
    for (int g = 0; g < 4; ++g) {
      int krow = g * 16 + rr;
      const int* p = w + (size_t)(kb + krow) * N_DIM + nb + cq * 4;
      int4 v = *(const int4*)p;            // coalesced along n
      tile[cq * 4 + 0][krow] = (f16)(float)v.x;
      tile[cq * 4 + 1][krow] = (f16)(float)v.y;
      tile[cq * 4 + 2][krow] = (f16)(float)v.z;
      tile[cq * 4 + 3][krow] = (f16)(float)v.w;
    }
    __syncthreads();
#pragma unroll
    for (int g = 0; g < 4; ++g) {
      int nrow = g * 16 + rr;
      f16x4 o;
#pragma unroll
      for (int j = 0; j < 4; ++j) o[j] = tile[nrow][cq * 4 + j];
      *(f16x4*)(wt + (size_t)(nb + nrow) * K_DIM + kb + cq * 4) = o;
    }
  } else {
    const int n8 = (M_TOK * K_DIM) / 8;
    const int nthreads = 4096 * 256;
    for (int i = (blockIdx.x - 1024) * 256 + tid; i < n8; i += nthreads) {
      float4 v0 = ((const float4*)x)[i * 2];
      float4 v1 = ((const float4*)x)[i * 2 + 1];
      f16x8 h;
      h[0] = (f16)v0.x; h[1] = (f16)v0.y; h[2] = (f16)v0.z; h[3] = (f16)v0.w;
      h[4] = (f16)v1.x; h[5] = (f16)v1.y; h[6] = (f16)v1.z; h[7] = (f16)v1.w;
      ((f16x8*)xh)[i] = h;
    }
  }
}

// ---------------------------------------------------------------------------
// Main GEMM: 256x128 block, 4 waves (2x2), wave tile 128x64 = 8x4 MFMA accs.
// ---------------------------------------------------------------------------
__device__ __forceinline__ void async_load16(const void* g, void* l) {
  __builtin_amdgcn_global_load_lds((__attribute__((address_space(1))) void*)g,
                                   (__attribute__((address_space(3))) void*)l,
                                   16, 0, 0);
}

__global__ __launch_bounds__(256, 2) void gemm_f16(
    const f16* __restrict__ xh, const f16* __restrict__ wt,
    const float* __restrict__ scale, float* __restrict__ out) {
  __shared__ __align__(16) f16 sA[BM * BK];    // 16KB, [m][k], row = 64B
  __shared__ __align__(16) f16 sB[BN * BK];    // 8KB,  [n][k]

  const int tid = threadIdx.x;
  const int wave = tid >> 6;
  const int lane = tid & 63;
  const int m0 = blockIdx.y * BM;
  const int n0 = blockIdx.x * BN;
  const int wm = (wave & 1) * 128;   // 2x2 wave grid, wave tile 128x64
  const int wn = (wave >> 1) * 64;

  // DMA staging: A = 16 chunks of 1KB (16 rows), wave fills [4w, 4w+4);
  //              B = 8 chunks, wave fills [2w, 2w+2).
  // chunk c, lane i -> LDS row c*16 + i/4, k-offset (i%4)*8 (lane*16B rule)
  const int cA = wave * 4;
  const int cB = wave * 2;
  const int rsub = lane >> 2;              // 0..15
  const int kq8 = (lane & 3) * 8;
  const f16* gA = xh + (size_t)(m0 + cA * 16 + rsub) * K_DIM + kq8;
  const f16* gB = wt + (size_t)(n0 + cB * 16 + rsub) * K_DIM + kq8;
  f16* lA = sA + cA * 512;
  f16* lB = sB + cB * 512;

  // MFMA fragment geometry (16x16x32): [row=lane&15][k=(lane>>4)*8 + j]
  const int fr = lane & 15;
  const int fq = (lane >> 4) * 8;

  f32x4 acc[8][4] = {};

  for (int k0 = 0; k0 < K_DIM; k0 += BK) {
#pragma unroll
    for (int c = 0; c < 4; ++c)
      async_load16(gA + (size_t)c * 16 * K_DIM + k0, lA + c * 512);
#pragma unroll
    for (int c = 0; c < 2; ++c)
      async_load16(gB + (size_t)c * 16 * K_DIM + k0, lB + c * 512);
    __syncthreads();   // drains DMA -> tiles visible

    f16x8 a[8], b[4];
#pragma unroll
    for (int mm = 0; mm < 8; ++mm)
      a[mm] = *(const f16x8*)&sA[(wm + mm * 16 + fr) * BK + fq];
#pragma unroll
    for (int nn = 0; nn < 4; ++nn)
      b[nn] = *(const f16x8*)&sB[(wn + nn * 16 + fr) * BK + fq];

#pragma unroll
    for (int mm = 0; mm < 8; ++mm)
#pragma unroll
      for (int nn = 0; nn < 4; ++nn)
        acc[mm][nn] = __builtin_amdgcn_mfma_f32_16x16x32_f16(a[mm], b[nn], acc[mm][nn], 0, 0, 0);

    __syncthreads();   // protect LDS from next iteration's DMA
  }

  // Epilogue: C/D layout col(n)=lane&15, row(m)=(lane>>4)*4+reg; scale[n]
#pragma unroll
  for (int nn = 0; nn < 4; ++nn) {
    int col = n0 + wn + nn * 16 + fr;
    float s = scale[col];
#pragma unroll
    for (int mm = 0; mm < 8; ++mm) {
      int rbase = m0 + wm + mm * 16 + (lane >> 4) * 4;
      f32x4 v = acc[mm][nn];
#pragma unroll
      for (int r = 0; r < 4; ++r)
        out[(size_t)(rbase + r) * N_DIM + col] = v[r] * s;
    }
  }
}

// ---------------------------------------------------------------------------
extern "C" void kernel_launch(void* const* d_in, const int* in_sizes, int n_in,
                              void* d_out, int out_size, void* d_ws, size_t ws_size,
                              hipStream_t stream) {
  const float* x     = (const float*)d_in[0];
  const float* scale = (const float*)d_in[1];
  const int* w       = (const int*)d_in[2];   // integer inputs arrive as int32
  float* out         = (float*)d_out;

  // workspace: x_h f16 (64MB) | W^T f16 (8MB)
  char* ws = (char*)d_ws;
  f16* xh = (f16*)ws;
  f16* wt = (f16*)(ws + (size_t)M_TOK * K_DIM * 2);

  convert_kernel<<<5120, 256, 0, stream>>>(x, w, xh, wt);
  // grid.x = n-tiles (16): consecutive blocks share the 256-row A strip (L2/L3)
  gemm_f16<<<dim3(N_DIM / BN, M_TOK / BM), 256, 0, stream>>>(xh, wt, scale, out);
}